// Round 11
// baseline (5726.552 us; speedup 1.0000x reference)
//
#include <hip/hip_runtime.h>
#include <hip/hip_bf16.h>

#define SEQ 512
#define BATCH 64
#define IN_DIM 512
#define HID 1024
#define G3 3072          // 3*HID
#define MTOT 32768       // SEQ*BATCH
#define NWG 128

typedef float f32x4 __attribute__((ext_vector_type(4)));
typedef short s16x8 __attribute__((ext_vector_type(8)));

static __device__ __forceinline__ unsigned short f2bf(float f) {
  union { float f; unsigned u; } v; v.f = f;
  unsigned r = v.u + 0x7fffu + ((v.u >> 16) & 1u);
  return (unsigned short)(r >> 16);
}
static __device__ __forceinline__ float bf2f(unsigned short b) {
  union { unsigned u; float f; } v; v.u = ((unsigned)b) << 16;
  return v.f;
}

// ---------------- fp32 -> bf16 hi/lo split ----------------
__global__ __launch_bounds__(256) void split_kernel(const float* __restrict__ src,
    unsigned short* __restrict__ hi, unsigned short* __restrict__ lo, int n4) {
  int stride = gridDim.x * blockDim.x;
  for (int i = blockIdx.x * blockDim.x + threadIdx.x; i < n4; i += stride) {
    float4 v = ((const float4*)src)[i];
    ushort4 h, l;
    h.x = f2bf(v.x); l.x = f2bf(v.x - bf2f(h.x));
    h.y = f2bf(v.y); l.y = f2bf(v.y - bf2f(h.y));
    h.z = f2bf(v.z); l.z = f2bf(v.z - bf2f(h.z));
    h.w = f2bf(v.w); l.w = f2bf(v.w - bf2f(h.w));
    ((ushort4*)hi)[i] = h;
    ((ushort4*)lo)[i] = l;
  }
}

// ---------------- phase 1: gi = emb @ w_ih^T + b_ih  (3-pass hi/lo split) ----
__global__ __launch_bounds__(256) void gemm_gi(
    const unsigned short* __restrict__ Ahi, const unsigned short* __restrict__ Alo,
    const unsigned short* __restrict__ Bhi, const unsigned short* __restrict__ Blo,
    const float* __restrict__ bih,
    float* __restrict__ gi32, unsigned short* __restrict__ gi16, int gi_is_f32)
{
  __shared__ unsigned short Al[128 * 64];
  __shared__ unsigned short Bl[128 * 64];
  const int tid = threadIdx.x;
  const int wave = tid >> 6, lane = tid & 63;
  const int bm0 = blockIdx.x * 128, bn0 = blockIdx.y * 128;
  const int wm = (wave >> 1) * 64, wn = (wave & 1) * 64;
  const int row16 = lane & 15, kq = lane >> 4;
  const int srow = tid >> 3;
  const int skc = tid & 7;

  f32x4 acc[4][4] = {};
  for (int p = 0; p < 3; ++p) {
    const unsigned short* Ap = (p == 1) ? Alo : Ahi;
    const unsigned short* Bp = (p == 2) ? Blo : Bhi;
    for (int kt = 0; kt < IN_DIM / 64; ++kt) {
      uint4 ar[4], br[4];
      for (int i = 0; i < 4; ++i) {
        int r = i * 32 + srow;
        ar[i] = *(const uint4*)&Ap[(size_t)(bm0 + r) * IN_DIM + kt * 64 + skc * 8];
        br[i] = *(const uint4*)&Bp[(size_t)(bn0 + r) * IN_DIM + kt * 64 + skc * 8];
      }
      __syncthreads();
      for (int i = 0; i < 4; ++i) {
        int r = i * 32 + srow;
        *(uint4*)&Al[r * 64 + skc * 8] = ar[i];
        *(uint4*)&Bl[r * 64 + skc * 8] = br[i];
      }
      __syncthreads();
      for (int kk = 0; kk < 2; ++kk) {
        s16x8 af[4], bf[4];
        for (int mi = 0; mi < 4; ++mi)
          af[mi] = *(const s16x8*)&Al[(wm + mi * 16 + row16) * 64 + kk * 32 + kq * 8];
        for (int ni = 0; ni < 4; ++ni)
          bf[ni] = *(const s16x8*)&Bl[(wn + ni * 16 + row16) * 64 + kk * 32 + kq * 8];
        for (int mi = 0; mi < 4; ++mi)
          for (int ni = 0; ni < 4; ++ni)
            acc[mi][ni] = __builtin_amdgcn_mfma_f32_16x16x32_bf16(af[mi], bf[ni], acc[mi][ni], 0, 0, 0);
      }
    }
  }
  for (int mi = 0; mi < 4; ++mi) {
    int grow0 = bm0 + wm + mi * 16 + kq * 4;
    for (int ni = 0; ni < 4; ++ni) {
      int gcol = bn0 + wn + ni * 16 + row16;
      float bias = bih[gcol];
#pragma unroll
      for (int q = 0; q < 4; ++q) {
        float v = acc[mi][ni][q] + bias;
        size_t off = (size_t)(grow0 + q) * G3 + gcol;
        if (gi_is_f32) gi32[off] = v;
        else gi16[off] = f2bf(v);
      }
    }
  }
}

// ---------------- persistent GRU scan (W-in-VGPR + flag-store barrier) ------
// 128 WGs x 512 thr. WG owns 8 hidden units; each lane's 32 W fragments live
// in registers (staged via LDS once) -> K-loop is {global h load -> MFMA},
// zero LDS reads. Waves: mt = wave&3 (16-batch tile), kh = wave>>2 (K half).
// Barrier: RMW-FREE. Arrive = one ushort flag store per WG (128 flags, 256B,
// distinct addresses -> no L3 RMW serialization, no aggregator hop). Poll =
// wave 0, lane-parallel: lane L loads dword (flags 2L,2L+1), __all(>= s).
// Flags monotonic (store s+1, poll >= s; max skew 1 step; 512 < 65536 so no
// wrap). All sc0 sc1 (write-through coherent point); all-relaxed semantics --
// causal order: h stores acked (vmcnt) -> syncthreads -> flag store -> poll
// observes -> dependent h loads. Proven structure from rounds 6-10.

#define LDH(dst, OFFS) asm volatile("global_load_dwordx4 %0, %1, off offset:" OFFS " sc0 sc1" : "=v"(dst) : "v"(hadr))
#define WAITV(N) do { asm volatile("s_waitcnt vmcnt(" #N ")" ::: "memory"); __builtin_amdgcn_sched_barrier(0); } while (0)
#define MMK(AH, KIDX) do { \
    acc0 = __builtin_amdgcn_mfma_f32_16x16x32_bf16(AH, wr[2*(KIDX)], acc0, 0, 0, 0); \
    acc1 = __builtin_amdgcn_mfma_f32_16x16x32_bf16(AH, wr[2*(KIDX)+1], acc1, 0, 0, 0); \
  } while (0)

__global__ __launch_bounds__(512, 2) void gru_persist(
    const unsigned short* __restrict__ Whh_hi,
    const float* __restrict__ gi32, const unsigned short* __restrict__ gi16, int gi_is_f32,
    const float* __restrict__ bhh,
    unsigned short* __restrict__ h0hi, unsigned short* __restrict__ h1hi,
    unsigned* __restrict__ bar,
    float* __restrict__ out, float* __restrict__ hidden)
{
  __shared__ unsigned short wl[2 * 24 * 1024];  // 96KB declared (pins 1 WG/CU); hi half used
  __shared__ float ghl2[2][64][24];             // 12KB (K-split partials)
  __shared__ float hown[512];                   // own h slice, fp32
  const int tid = threadIdx.x;
  const int wg = blockIdx.x;
  const int j0 = wg * 8;

  // stage w_hh HI once: 24 rows x 1024 elems = 3072 16B-chunks, 6 per thread
  for (int i = 0; i < 6; ++i) {
    int c = i * 512 + tid;
    int col = c >> 7;
    int kb = c & 127;
    int gate = col >> 3, uu = col & 7;
    const unsigned short* src = Whh_hi + (size_t)(gate * HID + j0 + uu) * HID + kb * 8;
    int byte = col * 2048 + ((kb * 16) ^ ((col & 7) << 4));
    *(uint4*)((char*)wl + byte) = *(const uint4*)src;
  }
  hown[tid] = 0.f;

  const int wave = tid >> 6, lane = tid & 63;
  const int mt = wave & 3, kh = wave >> 2;
  const int row16 = lane & 15, kq = lane >> 4;
  const int b = mt * 16 + row16;
  const int cc0 = row16;
  const int cc1 = 16 + (row16 & 7);
  const int xr = (row16 & 7) << 4;
  const char* wbase = (const char*)wl;
  const unsigned hvoff = (unsigned)(b * 2048 + kh * 1024 + kq * 16);

  const int b2 = tid >> 3, u = tid & 7, j = j0 + u;
  const float bh_r = bhh[j], bh_z = bhh[HID + j], bh_n = bhh[2 * HID + j];

  // barrier state: 128 ushort flags (256B) at bar
  const unsigned long long flagbase = (unsigned long long)bar;
  const unsigned long long myflag = flagbase + (unsigned)(wg * 2);
  const unsigned long long pollad = flagbase + (unsigned)(lane * 4);  // wave-0 lane L: flags 2L,2L+1

  __syncthreads();

  // hoist this lane's W fragments into registers (static indices -> regalloc)
  s16x8 wr[32];
#pragma unroll
  for (int kidx = 0; kidx < 16; ++kidx) {
    int wb = (kh << 10) + kidx * 64 + (kq << 4);
    wr[2 * kidx]     = *(const s16x8*)(wbase + (cc0 << 11) + (wb ^ xr));
    wr[2 * kidx + 1] = *(const s16x8*)(wbase + (cc1 << 11) + (wb ^ xr));
  }

  for (int s = 0; s < SEQ; ++s) {
    const unsigned short* hi_in = (s & 1) ? h1hi : h0hi;
    unsigned short* hi_out = (s & 1) ? h0hi : h1hi;
    unsigned long long hadr = (unsigned long long)hi_in + hvoff;

    // gi prefetch (independent of h -> issue before barrier spin)
    float gir = 0.f, giz = 0.f, gin_ = 0.f;
    unsigned short g16r = 0, g16z = 0, g16n = 0;
    if (gi_is_f32) {
      unsigned long long ga = (unsigned long long)(gi32 + (size_t)(s * BATCH + b2) * G3 + j);
      asm volatile("global_load_dword %0, %1, off" : "=v"(gir) : "v"(ga));
      asm volatile("global_load_dword %0, %1, off" : "=v"(giz) : "v"(ga + 4096ull));
      asm volatile("global_load_dword %0, %1, off" : "=v"(gin_) : "v"(ga + 8192ull));
    } else {
      unsigned long long ga = (unsigned long long)(gi16 + (size_t)(s * BATCH + b2) * G3 + j);
      asm volatile("global_load_ushort %0, %1, off" : "=v"(g16r) : "v"(ga));
      asm volatile("global_load_ushort %0, %1, off" : "=v"(g16z) : "v"(ga + 2048ull));
      asm volatile("global_load_ushort %0, %1, off" : "=v"(g16n) : "v"(ga + 4096ull));
    }

    // grid barrier wait: wave 0 lane-parallel poll of 128 ushort flags
    if (wave == 0) {
      const unsigned exp = (unsigned)s;
      for (;;) {
        unsigned f;
        asm volatile("global_load_dword %0, %1, off sc0 sc1\n\t"
                     "s_waitcnt vmcnt(0)"
                     : "=v"(f) : "v"(pollad) : "memory");
        int ok = ((f & 0xffffu) >= exp) && ((f >> 16) >= exp);
        if (__all(ok)) break;
      }
    }
    __syncthreads();

    // pipelined h loads (sc0 sc1) + MFMA, both MFMA operands in registers
    f32x4 acc0 = {0.f, 0.f, 0.f, 0.f}, acc1 = {0.f, 0.f, 0.f, 0.f};
    s16x8 a0, a1, a2, a3, a4, a5, a6, a7, a8, a9, a10, a11, a12, a13, a14, a15;
    LDH(a0, "0");    LDH(a1, "64");   LDH(a2, "128");  LDH(a3, "192");
    LDH(a4, "256");  LDH(a5, "320");  LDH(a6, "384");  LDH(a7, "448");
    LDH(a8, "512");  LDH(a9, "576");  LDH(a10, "640"); LDH(a11, "704");
    LDH(a12, "768"); LDH(a13, "832"); LDH(a14, "896"); LDH(a15, "960");
    WAITV(12);
    MMK(a0, 0); MMK(a1, 1); MMK(a2, 2); MMK(a3, 3);
    WAITV(8);
    MMK(a4, 4); MMK(a5, 5); MMK(a6, 6); MMK(a7, 7);
    WAITV(4);
    MMK(a8, 8); MMK(a9, 9); MMK(a10, 10); MMK(a11, 11);
    WAITV(0);
    MMK(a12, 12); MMK(a13, 13); MMK(a14, 14); MMK(a15, 15);

#pragma unroll
    for (int q = 0; q < 4; ++q)
      ghl2[kh][mt * 16 + kq * 4 + q][row16] = acc0[q];
    if (row16 < 8) {
#pragma unroll
      for (int q = 0; q < 4; ++q)
        ghl2[kh][mt * 16 + kq * 4 + q][16 + row16] = acc1[q];
    }
    __syncthreads();

    // gating
    float ir, iz, inn;
    if (gi_is_f32) { ir = gir; iz = giz; inn = gin_; }
    else { ir = bf2f(g16r); iz = bf2f(g16z); inn = bf2f(g16n); }
    float hr = ghl2[0][b2][u]      + ghl2[1][b2][u]      + bh_r;
    float hz = ghl2[0][b2][8 + u]  + ghl2[1][b2][8 + u]  + bh_z;
    float hn = ghl2[0][b2][16 + u] + ghl2[1][b2][16 + u] + bh_n;
    float r = 1.f / (1.f + __expf(-(ir + hr)));
    float z = 1.f / (1.f + __expf(-(iz + hz)));
    float n = tanhf(inn + r * hn);
    float hp = hown[tid];
    float h = (1.f - z) * n + z * hp;
    hown[tid] = h;
    // h store FIRST (gates the flag), then out/hidden (drain later)
    unsigned short hb = f2bf(h);
    unsigned hv = (unsigned)(b2 * 1024 + j) * 2u;
    unsigned long long sha = (unsigned long long)hi_out + hv;
    asm volatile("global_store_short %0, %1, off sc0 sc1" :: "v"(sha), "v"(hb) : "memory");
    out[((size_t)b2 * SEQ + s) * HID + j] = h;
    if (s == SEQ - 1) hidden[(size_t)b2 * HID + j] = h;
    // wait for the h store (oldest); the out store may keep draining
    asm volatile("s_waitcnt vmcnt(1)" ::: "memory");
    __syncthreads();   // all 512 h stores of this WG acked

    // arrive: ONE flag store, no RMW, no aggregation hop
    if (tid == 0) {
      unsigned short fv = (unsigned short)(s + 1);
      asm volatile("global_store_short %0, %1, off sc0 sc1" :: "v"(myflag), "v"(fv) : "memory");
    }
  }
}

extern "C" void kernel_launch(void* const* d_in, const int* in_sizes, int n_in,
                              void* d_out, int out_size, void* d_ws, size_t ws_size,
                              hipStream_t stream) {
  const float* emb = (const float*)d_in[0];
  const float* wih = (const float*)d_in[1];
  const float* whh = (const float*)d_in[2];
  const float* bih = (const float*)d_in[3];
  const float* bhh = (const float*)d_in[4];
  float* out = (float*)d_out;                          // [64][512][1024]
  float* hidden = out + (size_t)BATCH * SEQ * HID;     // [64][1024]

  char* ws = (char*)d_ws;
  size_t off = 0;
  auto alloc = [&](size_t bytes) {
    char* p = ws + off;
    off += (bytes + 255) & ~(size_t)255;
    return p;
  };

  unsigned short* emb_hi = (unsigned short*)alloc((size_t)MTOT * IN_DIM * 2);
  unsigned short* emb_lo = (unsigned short*)alloc((size_t)MTOT * IN_DIM * 2);
  unsigned short* wih_hi = (unsigned short*)alloc((size_t)G3 * IN_DIM * 2);
  unsigned short* wih_lo = (unsigned short*)alloc((size_t)G3 * IN_DIM * 2);
  unsigned short* whh_hi = (unsigned short*)alloc((size_t)G3 * HID * 2);
  unsigned short* whh_lo = (unsigned short*)alloc((size_t)G3 * HID * 2);
  unsigned short* hbuf   = (unsigned short*)alloc((size_t)2 * BATCH * HID * 2);
  unsigned* bar = (unsigned*)alloc(4096);

  size_t gi32_bytes = (size_t)MTOT * G3 * 4;
  int gi_is_f32 = (off + gi32_bytes <= ws_size) ? 1 : 0;
  float* gi32 = nullptr;
  unsigned short* gi16 = nullptr;
  if (gi_is_f32) gi32 = (float*)alloc(gi32_bytes);
  else           gi16 = (unsigned short*)alloc((size_t)MTOT * G3 * 2);

  // converts
  split_kernel<<<4096, 256, 0, stream>>>(emb, emb_hi, emb_lo, MTOT * IN_DIM / 4);
  split_kernel<<<1536, 256, 0, stream>>>(wih, wih_hi, wih_lo, G3 * IN_DIM / 4);
  split_kernel<<<3072, 256, 0, stream>>>(whh, whh_hi, whh_lo, G3 * HID / 4);

  // zero h state (h0 = 0) + flags (must restart at 0 every call/replay)
  (void)hipMemsetAsync(hbuf, 0, (size_t)2 * BATCH * HID * 2, stream);
  (void)hipMemsetAsync(bar, 0, 4096, stream);

  // phase 1 GEMM
  dim3 g1(MTOT / 128, G3 / 128);
  gemm_gi<<<g1, 256, 0, stream>>>(emb_hi, emb_lo, wih_hi, wih_lo, bih, gi32, gi16, gi_is_f32);

  // persistent scan (cooperative: guarantees all 128 WGs co-resident)
  size_t BH = (size_t)BATCH * HID;
  unsigned short* h0hi = hbuf;
  unsigned short* h1hi = hbuf + BH;
  void* args[] = { &whh_hi, &gi32, &gi16, &gi_is_f32, &bhh,
                   &h0hi, &h1hi, &bar, &out, &hidden };
  (void)hipLaunchCooperativeKernel((void*)gru_persist, dim3(NWG), dim3(512), args, 0, stream);
}

// Round 12
// 4495.269 us; speedup vs baseline: 1.2739x; 1.2739x over previous
//
#include <hip/hip_runtime.h>
#include <hip/hip_bf16.h>

#define SEQ 512
#define BATCH 64
#define IN_DIM 512
#define HID 1024
#define G3 3072          // 3*HID
#define MTOT 32768       // SEQ*BATCH
#define NWG 128

typedef float f32x4 __attribute__((ext_vector_type(4)));
typedef short s16x8 __attribute__((ext_vector_type(8)));

static __device__ __forceinline__ unsigned short f2bf(float f) {
  union { float f; unsigned u; } v; v.f = f;
  unsigned r = v.u + 0x7fffu + ((v.u >> 16) & 1u);
  return (unsigned short)(r >> 16);
}
static __device__ __forceinline__ float bf2f(unsigned short b) {
  union { unsigned u; float f; } v; v.u = ((unsigned)b) << 16;
  return v.f;
}
static __device__ __forceinline__ unsigned umin2(unsigned a, unsigned b) { return a < b ? a : b; }

// ---------------- fp32 -> bf16 hi/lo split ----------------
__global__ __launch_bounds__(256) void split_kernel(const float* __restrict__ src,
    unsigned short* __restrict__ hi, unsigned short* __restrict__ lo, int n4) {
  int stride = gridDim.x * blockDim.x;
  for (int i = blockIdx.x * blockDim.x + threadIdx.x; i < n4; i += stride) {
    float4 v = ((const float4*)src)[i];
    ushort4 h, l;
    h.x = f2bf(v.x); l.x = f2bf(v.x - bf2f(h.x));
    h.y = f2bf(v.y); l.y = f2bf(v.y - bf2f(h.y));
    h.z = f2bf(v.z); l.z = f2bf(v.z - bf2f(h.z));
    h.w = f2bf(v.w); l.w = f2bf(v.w - bf2f(h.w));
    ((ushort4*)hi)[i] = h;
    ((ushort4*)lo)[i] = l;
  }
}

// ---------------- phase 1: gi = emb @ w_ih^T + b_ih ----------------
// Hi/lo 3-product split, STAGE-ONCE: per K-tile all 4 tiles (Ahi,Alo,Bhi,Blo)
// staged to LDS once; 3 MFMA products per fragment pair. vs the 3-pass
// version: staging 96->64KB/kt, barriers 48->16, ds_reads 384->256.
__global__ __launch_bounds__(256) void gemm_gi(
    const unsigned short* __restrict__ Ahi, const unsigned short* __restrict__ Alo,
    const unsigned short* __restrict__ Bhi, const unsigned short* __restrict__ Blo,
    const float* __restrict__ bih,
    float* __restrict__ gi32, unsigned short* __restrict__ gi16, int gi_is_f32)
{
  __shared__ unsigned short Ah[128 * 64];
  __shared__ unsigned short Alo_[128 * 64];
  __shared__ unsigned short Bh[128 * 64];
  __shared__ unsigned short Blo_[128 * 64];
  const int tid = threadIdx.x;
  const int wave = tid >> 6, lane = tid & 63;
  const int bm0 = blockIdx.x * 128, bn0 = blockIdx.y * 128;
  const int wm = (wave >> 1) * 64, wn = (wave & 1) * 64;
  const int row16 = lane & 15, kq = lane >> 4;
  const int srow = tid >> 3;   // 0..31
  const int skc = tid & 7;     // 16B chunk within 128B row

  f32x4 acc[4][4] = {};
  for (int kt = 0; kt < IN_DIM / 64; ++kt) {
    uint4 rah[4], ral[4], rbh[4], rbl[4];
    for (int i = 0; i < 4; ++i) {
      int r = i * 32 + srow;
      size_t ao = (size_t)(bm0 + r) * IN_DIM + kt * 64 + skc * 8;
      size_t bo = (size_t)(bn0 + r) * IN_DIM + kt * 64 + skc * 8;
      rah[i] = *(const uint4*)&Ahi[ao];
      ral[i] = *(const uint4*)&Alo[ao];
      rbh[i] = *(const uint4*)&Bhi[bo];
      rbl[i] = *(const uint4*)&Blo[bo];
    }
    __syncthreads();
    for (int i = 0; i < 4; ++i) {
      int r = i * 32 + srow;
      *(uint4*)&Ah[r * 64 + skc * 8]   = rah[i];
      *(uint4*)&Alo_[r * 64 + skc * 8] = ral[i];
      *(uint4*)&Bh[r * 64 + skc * 8]   = rbh[i];
      *(uint4*)&Blo_[r * 64 + skc * 8] = rbl[i];
    }
    __syncthreads();
    for (int kk = 0; kk < 2; ++kk) {
      s16x8 ah[4], al[4], bh[4], bl[4];
      for (int mi = 0; mi < 4; ++mi) {
        int off = (wm + mi * 16 + row16) * 64 + kk * 32 + kq * 8;
        ah[mi] = *(const s16x8*)&Ah[off];
        al[mi] = *(const s16x8*)&Alo_[off];
      }
      for (int ni = 0; ni < 4; ++ni) {
        int off = (wn + ni * 16 + row16) * 64 + kk * 32 + kq * 8;
        bh[ni] = *(const s16x8*)&Bh[off];
        bl[ni] = *(const s16x8*)&Blo_[off];
      }
      for (int mi = 0; mi < 4; ++mi)
        for (int ni = 0; ni < 4; ++ni) {
          acc[mi][ni] = __builtin_amdgcn_mfma_f32_16x16x32_bf16(ah[mi], bh[ni], acc[mi][ni], 0, 0, 0);
          acc[mi][ni] = __builtin_amdgcn_mfma_f32_16x16x32_bf16(al[mi], bh[ni], acc[mi][ni], 0, 0, 0);
          acc[mi][ni] = __builtin_amdgcn_mfma_f32_16x16x32_bf16(ah[mi], bl[ni], acc[mi][ni], 0, 0, 0);
        }
    }
  }
  for (int mi = 0; mi < 4; ++mi) {
    int grow0 = bm0 + wm + mi * 16 + kq * 4;
    for (int ni = 0; ni < 4; ++ni) {
      int gcol = bn0 + wn + ni * 16 + row16;
      float bias = bih[gcol];
#pragma unroll
      for (int q = 0; q < 4; ++q) {
        float v = acc[mi][ni][q] + bias;
        size_t off = (size_t)(grow0 + q) * G3 + gcol;
        if (gi_is_f32) gi32[off] = v;
        else gi16[off] = f2bf(v);
      }
    }
  }
}

// ---------------- persistent GRU scan (round-10 structure, best measured) ---
// 128 WGs x 512 thr. WG owns 8 hidden units; each lane's 32 W fragments in
// VGPRs (staged via LDS once) -> K-loop is {global h load -> MFMA}, zero LDS
// reads. Waves: mt = wave&3 (16-batch tile), kh = wave>>2 (K half).
// h broadcast: bf16 hi only. Barrier: flat relaxed monotonic RMW arrive
// (8 group counters, 16 WGs each) + tid0 poll of 8 packed gen counters (32B).

#define LDH(dst, OFFS) asm volatile("global_load_dwordx4 %0, %1, off offset:" OFFS " sc0 sc1" : "=v"(dst) : "v"(hadr))
#define WAITV(N) do { asm volatile("s_waitcnt vmcnt(" #N ")" ::: "memory"); __builtin_amdgcn_sched_barrier(0); } while (0)
#define MMK(AH, KIDX) do { \
    acc0 = __builtin_amdgcn_mfma_f32_16x16x32_bf16(AH, wr[2*(KIDX)], acc0, 0, 0, 0); \
    acc1 = __builtin_amdgcn_mfma_f32_16x16x32_bf16(AH, wr[2*(KIDX)+1], acc1, 0, 0, 0); \
  } while (0)

__global__ __launch_bounds__(512, 2) void gru_persist(
    const unsigned short* __restrict__ Whh_hi,
    const float* __restrict__ gi32, const unsigned short* __restrict__ gi16, int gi_is_f32,
    const float* __restrict__ bhh,
    unsigned short* __restrict__ h0hi, unsigned short* __restrict__ h1hi,
    unsigned* __restrict__ bar,
    float* __restrict__ out, float* __restrict__ hidden)
{
  __shared__ unsigned short wl[2 * 24 * 1024];  // 96KB declared (pins 1 WG/CU); hi half used
  __shared__ float ghl2[2][64][24];             // 12KB (K-split partials)
  __shared__ float hown[512];                   // own h slice, fp32
  const int tid = threadIdx.x;
  const int wg = blockIdx.x;
  const int j0 = wg * 8;

  // stage w_hh HI once: 24 rows x 1024 elems = 3072 16B-chunks, 6 per thread
  for (int i = 0; i < 6; ++i) {
    int c = i * 512 + tid;
    int col = c >> 7;
    int kb = c & 127;
    int gate = col >> 3, uu = col & 7;
    const unsigned short* src = Whh_hi + (size_t)(gate * HID + j0 + uu) * HID + kb * 8;
    int byte = col * 2048 + ((kb * 16) ^ ((col & 7) << 4));
    *(uint4*)((char*)wl + byte) = *(const uint4*)src;
  }
  hown[tid] = 0.f;

  const int wave = tid >> 6, lane = tid & 63;
  const int mt = wave & 3, kh = wave >> 2;
  const int row16 = lane & 15, kq = lane >> 4;
  const int b = mt * 16 + row16;
  const int cc0 = row16;
  const int cc1 = 16 + (row16 & 7);
  const int xr = (row16 & 7) << 4;
  const char* wbase = (const char*)wl;
  const unsigned hvoff = (unsigned)(b * 2048 + kh * 1024 + kq * 16);

  const int b2 = tid >> 3, u = tid & 7, j = j0 + u;
  const float bh_r = bhh[j], bh_z = bhh[HID + j], bh_n = bhh[2 * HID + j];

  unsigned* cA = bar;            // 8 monotonic counters, 128B apart (idx g*32)
  unsigned* genv = bar + 320;    // 8 packed gen counters (32B)

  __syncthreads();

  // hoist this lane's W fragments into registers (static indices -> regalloc)
  s16x8 wr[32];
#pragma unroll
  for (int kidx = 0; kidx < 16; ++kidx) {
    int wb = (kh << 10) + kidx * 64 + (kq << 4);
    wr[2 * kidx]     = *(const s16x8*)(wbase + (cc0 << 11) + (wb ^ xr));
    wr[2 * kidx + 1] = *(const s16x8*)(wbase + (cc1 << 11) + (wb ^ xr));
  }

  for (int s = 0; s < SEQ; ++s) {
    const unsigned short* hi_in = (s & 1) ? h1hi : h0hi;
    unsigned short* hi_out = (s & 1) ? h0hi : h1hi;
    unsigned long long hadr = (unsigned long long)hi_in + hvoff;

    // gi prefetch (independent of h -> issue before barrier spin)
    float gir = 0.f, giz = 0.f, gin_ = 0.f;
    unsigned short g16r = 0, g16z = 0, g16n = 0;
    if (gi_is_f32) {
      unsigned long long ga = (unsigned long long)(gi32 + (size_t)(s * BATCH + b2) * G3 + j);
      asm volatile("global_load_dword %0, %1, off" : "=v"(gir) : "v"(ga));
      asm volatile("global_load_dword %0, %1, off" : "=v"(giz) : "v"(ga + 4096ull));
      asm volatile("global_load_dword %0, %1, off" : "=v"(gin_) : "v"(ga + 8192ull));
    } else {
      unsigned long long ga = (unsigned long long)(gi16 + (size_t)(s * BATCH + b2) * G3 + j);
      asm volatile("global_load_ushort %0, %1, off" : "=v"(g16r) : "v"(ga));
      asm volatile("global_load_ushort %0, %1, off" : "=v"(g16z) : "v"(ga + 2048ull));
      asm volatile("global_load_ushort %0, %1, off" : "=v"(g16n) : "v"(ga + 4096ull));
    }

    // grid barrier wait: all 8 genv >= s (two b128 sc0sc1 loads per poll)
    if (tid == 0) {
      unsigned long long gva = (unsigned long long)genv;
      for (;;) {
        uint4 g01, g23;
        asm volatile("global_load_dwordx4 %0, %2, off sc0 sc1\n\t"
                     "global_load_dwordx4 %1, %2, off offset:16 sc0 sc1\n\t"
                     "s_waitcnt vmcnt(0)"
                     : "=v"(g01), "=v"(g23) : "v"(gva) : "memory");
        unsigned mn = umin2(umin2(umin2(g01.x, g01.y), umin2(g01.z, g01.w)),
                            umin2(umin2(g23.x, g23.y), umin2(g23.z, g23.w)));
        if (mn >= (unsigned)s) break;
      }
    }
    __syncthreads();

    // pipelined h loads (sc0 sc1) + MFMA, both MFMA operands in registers
    f32x4 acc0 = {0.f, 0.f, 0.f, 0.f}, acc1 = {0.f, 0.f, 0.f, 0.f};
    s16x8 a0, a1, a2, a3, a4, a5, a6, a7, a8, a9, a10, a11, a12, a13, a14, a15;
    LDH(a0, "0");    LDH(a1, "64");   LDH(a2, "128");  LDH(a3, "192");
    LDH(a4, "256");  LDH(a5, "320");  LDH(a6, "384");  LDH(a7, "448");
    LDH(a8, "512");  LDH(a9, "576");  LDH(a10, "640"); LDH(a11, "704");
    LDH(a12, "768"); LDH(a13, "832"); LDH(a14, "896"); LDH(a15, "960");
    WAITV(12);
    MMK(a0, 0); MMK(a1, 1); MMK(a2, 2); MMK(a3, 3);
    WAITV(8);
    MMK(a4, 4); MMK(a5, 5); MMK(a6, 6); MMK(a7, 7);
    WAITV(4);
    MMK(a8, 8); MMK(a9, 9); MMK(a10, 10); MMK(a11, 11);
    WAITV(0);
    MMK(a12, 12); MMK(a13, 13); MMK(a14, 14); MMK(a15, 15);

#pragma unroll
    for (int q = 0; q < 4; ++q)
      ghl2[kh][mt * 16 + kq * 4 + q][row16] = acc0[q];
    if (row16 < 8) {
#pragma unroll
      for (int q = 0; q < 4; ++q)
        ghl2[kh][mt * 16 + kq * 4 + q][16 + row16] = acc1[q];
    }
    __syncthreads();

    // gating
    float ir, iz, inn;
    if (gi_is_f32) { ir = gir; iz = giz; inn = gin_; }
    else { ir = bf2f(g16r); iz = bf2f(g16z); inn = bf2f(g16n); }
    float hr = ghl2[0][b2][u]      + ghl2[1][b2][u]      + bh_r;
    float hz = ghl2[0][b2][8 + u]  + ghl2[1][b2][8 + u]  + bh_z;
    float hn = ghl2[0][b2][16 + u] + ghl2[1][b2][16 + u] + bh_n;
    float r = 1.f / (1.f + __expf(-(ir + hr)));
    float z = 1.f / (1.f + __expf(-(iz + hz)));
    float n = tanhf(inn + r * hn);
    float hp = hown[tid];
    float h = (1.f - z) * n + z * hp;
    hown[tid] = h;
    // h store FIRST (gates the barrier), then out/hidden (drain later)
    unsigned short hb = f2bf(h);
    unsigned hv = (unsigned)(b2 * 1024 + j) * 2u;
    unsigned long long sha = (unsigned long long)hi_out + hv;
    asm volatile("global_store_short %0, %1, off sc0 sc1" :: "v"(sha), "v"(hb) : "memory");
    out[((size_t)b2 * SEQ + s) * HID + j] = h;
    if (s == SEQ - 1) hidden[(size_t)b2 * HID + j] = h;
    // wait only for the h store (oldest); the out store may keep draining
    asm volatile("s_waitcnt vmcnt(1)" ::: "memory");
    __syncthreads();

    // grid barrier arrive: relaxed monotonic; group-complete writes genv[g]
    if (tid == 0) {
      int g = wg & 7;
      unsigned a = __hip_atomic_fetch_add(&cA[g * 32], 1u, __ATOMIC_RELAXED, __HIP_MEMORY_SCOPE_AGENT);
      if (a + 1u == 16u * (unsigned)(s + 1)) {
        __hip_atomic_store(&genv[g], (unsigned)(s + 1), __ATOMIC_RELAXED, __HIP_MEMORY_SCOPE_AGENT);
      }
    }
  }
}

extern "C" void kernel_launch(void* const* d_in, const int* in_sizes, int n_in,
                              void* d_out, int out_size, void* d_ws, size_t ws_size,
                              hipStream_t stream) {
  const float* emb = (const float*)d_in[0];
  const float* wih = (const float*)d_in[1];
  const float* whh = (const float*)d_in[2];
  const float* bih = (const float*)d_in[3];
  const float* bhh = (const float*)d_in[4];
  float* out = (float*)d_out;                          // [64][512][1024]
  float* hidden = out + (size_t)BATCH * SEQ * HID;     // [64][1024]

  char* ws = (char*)d_ws;
  size_t off = 0;
  auto alloc = [&](size_t bytes) {
    char* p = ws + off;
    off += (bytes + 255) & ~(size_t)255;
    return p;
  };

  unsigned short* emb_hi = (unsigned short*)alloc((size_t)MTOT * IN_DIM * 2);
  unsigned short* emb_lo = (unsigned short*)alloc((size_t)MTOT * IN_DIM * 2);
  unsigned short* wih_hi = (unsigned short*)alloc((size_t)G3 * IN_DIM * 2);
  unsigned short* wih_lo = (unsigned short*)alloc((size_t)G3 * IN_DIM * 2);
  unsigned short* whh_hi = (unsigned short*)alloc((size_t)G3 * HID * 2);
  unsigned short* whh_lo = (unsigned short*)alloc((size_t)G3 * HID * 2);
  unsigned short* hbuf   = (unsigned short*)alloc((size_t)2 * BATCH * HID * 2);
  unsigned* bar = (unsigned*)alloc(4096);

  size_t gi32_bytes = (size_t)MTOT * G3 * 4;
  int gi_is_f32 = (off + gi32_bytes <= ws_size) ? 1 : 0;
  float* gi32 = nullptr;
  unsigned short* gi16 = nullptr;
  if (gi_is_f32) gi32 = (float*)alloc(gi32_bytes);
  else           gi16 = (unsigned short*)alloc((size_t)MTOT * G3 * 2);

  // converts
  split_kernel<<<4096, 256, 0, stream>>>(emb, emb_hi, emb_lo, MTOT * IN_DIM / 4);
  split_kernel<<<1536, 256, 0, stream>>>(wih, wih_hi, wih_lo, G3 * IN_DIM / 4);
  split_kernel<<<3072, 256, 0, stream>>>(whh, whh_hi, whh_lo, G3 * HID / 4);

  // zero h state (h0 = 0) + barrier state (counters must restart at 0 every call)
  (void)hipMemsetAsync(hbuf, 0, (size_t)2 * BATCH * HID * 2, stream);
  (void)hipMemsetAsync(bar, 0, 4096, stream);

  // phase 1 GEMM (stage-once hi/lo)
  dim3 g1(MTOT / 128, G3 / 128);
  gemm_gi<<<g1, 256, 0, stream>>>(emb_hi, emb_lo, wih_hi, wih_lo, bih, gi32, gi16, gi_is_f32);

  // persistent scan (cooperative: guarantees all 128 WGs co-resident)
  size_t BH = (size_t)BATCH * HID;
  unsigned short* h0hi = hbuf;
  unsigned short* h1hi = hbuf + BH;
  void* args[] = { &whh_hi, &gi32, &gi16, &gi_is_f32, &bhh,
                   &h0hi, &h1hi, &bar, &out, &hidden };
  (void)hipLaunchCooperativeKernel((void*)gru_persist, dim3(NWG), dim3(512), args, 0, stream);
}

// Round 13
// 2777.231 us; speedup vs baseline: 2.0620x; 1.6186x over previous
//
#include <hip/hip_runtime.h>
#include <hip/hip_bf16.h>

#define SEQ 512
#define BATCH 64
#define IN_DIM 512
#define HID 1024
#define G3 3072          // 3*HID
#define MTOT 32768       // SEQ*BATCH
#define NWG 128
#define GB 16            // batches per group (4 groups)
#define UPW 32           // hidden units per WG

typedef float f32x4 __attribute__((ext_vector_type(4)));
typedef short s16x8 __attribute__((ext_vector_type(8)));

static __device__ __forceinline__ unsigned short f2bf(float f) {
  union { float f; unsigned u; } v; v.f = f;
  unsigned r = v.u + 0x7fffu + ((v.u >> 16) & 1u);
  return (unsigned short)(r >> 16);
}
static __device__ __forceinline__ float bf2f(unsigned short b) {
  union { unsigned u; float f; } v; v.u = ((unsigned)b) << 16;
  return v.f;
}
static __device__ __forceinline__ unsigned umin2(unsigned a, unsigned b) { return a < b ? a : b; }

// ---------------- fp32 -> bf16 hi/lo split ----------------
__global__ __launch_bounds__(256) void split_kernel(const float* __restrict__ src,
    unsigned short* __restrict__ hi, unsigned short* __restrict__ lo, int n4) {
  int stride = gridDim.x * blockDim.x;
  for (int i = blockIdx.x * blockDim.x + threadIdx.x; i < n4; i += stride) {
    float4 v = ((const float4*)src)[i];
    ushort4 h, l;
    h.x = f2bf(v.x); l.x = f2bf(v.x - bf2f(h.x));
    h.y = f2bf(v.y); l.y = f2bf(v.y - bf2f(h.y));
    h.z = f2bf(v.z); l.z = f2bf(v.z - bf2f(h.z));
    h.w = f2bf(v.w); l.w = f2bf(v.w - bf2f(h.w));
    ((ushort4*)hi)[i] = h;
    ((ushort4*)lo)[i] = l;
  }
}

// ---------------- phase 1: gi = emb @ w_ih^T + b_ih (stage-once hi/lo) ------
__global__ __launch_bounds__(256) void gemm_gi(
    const unsigned short* __restrict__ Ahi, const unsigned short* __restrict__ Alo,
    const unsigned short* __restrict__ Bhi, const unsigned short* __restrict__ Blo,
    const float* __restrict__ bih,
    float* __restrict__ gi32, unsigned short* __restrict__ gi16, int gi_is_f32)
{
  __shared__ unsigned short Ah[128 * 64];
  __shared__ unsigned short Alo_[128 * 64];
  __shared__ unsigned short Bh[128 * 64];
  __shared__ unsigned short Blo_[128 * 64];
  const int tid = threadIdx.x;
  const int wave = tid >> 6, lane = tid & 63;
  const int bm0 = blockIdx.x * 128, bn0 = blockIdx.y * 128;
  const int wm = (wave >> 1) * 64, wn = (wave & 1) * 64;
  const int row16 = lane & 15, kq = lane >> 4;
  const int srow = tid >> 3;
  const int skc = tid & 7;

  f32x4 acc[4][4] = {};
  for (int kt = 0; kt < IN_DIM / 64; ++kt) {
    uint4 rah[4], ral[4], rbh[4], rbl[4];
    for (int i = 0; i < 4; ++i) {
      int r = i * 32 + srow;
      size_t ao = (size_t)(bm0 + r) * IN_DIM + kt * 64 + skc * 8;
      size_t bo = (size_t)(bn0 + r) * IN_DIM + kt * 64 + skc * 8;
      rah[i] = *(const uint4*)&Ahi[ao];
      ral[i] = *(const uint4*)&Alo[ao];
      rbh[i] = *(const uint4*)&Bhi[bo];
      rbl[i] = *(const uint4*)&Blo[bo];
    }
    __syncthreads();
    for (int i = 0; i < 4; ++i) {
      int r = i * 32 + srow;
      *(uint4*)&Ah[r * 64 + skc * 8]   = rah[i];
      *(uint4*)&Alo_[r * 64 + skc * 8] = ral[i];
      *(uint4*)&Bh[r * 64 + skc * 8]   = rbh[i];
      *(uint4*)&Blo_[r * 64 + skc * 8] = rbl[i];
    }
    __syncthreads();
    for (int kk = 0; kk < 2; ++kk) {
      s16x8 ah[4], al[4], bh[4], bl[4];
      for (int mi = 0; mi < 4; ++mi) {
        int off = (wm + mi * 16 + row16) * 64 + kk * 32 + kq * 8;
        ah[mi] = *(const s16x8*)&Ah[off];
        al[mi] = *(const s16x8*)&Alo_[off];
      }
      for (int ni = 0; ni < 4; ++ni) {
        int off = (wn + ni * 16 + row16) * 64 + kk * 32 + kq * 8;
        bh[ni] = *(const s16x8*)&Bh[off];
        bl[ni] = *(const s16x8*)&Blo_[off];
      }
      for (int mi = 0; mi < 4; ++mi)
        for (int ni = 0; ni < 4; ++ni) {
          acc[mi][ni] = __builtin_amdgcn_mfma_f32_16x16x32_bf16(ah[mi], bh[ni], acc[mi][ni], 0, 0, 0);
          acc[mi][ni] = __builtin_amdgcn_mfma_f32_16x16x32_bf16(al[mi], bh[ni], acc[mi][ni], 0, 0, 0);
          acc[mi][ni] = __builtin_amdgcn_mfma_f32_16x16x32_bf16(ah[mi], bl[ni], acc[mi][ni], 0, 0, 0);
        }
    }
  }
  for (int mi = 0; mi < 4; ++mi) {
    int grow0 = bm0 + wm + mi * 16 + kq * 4;
    for (int ni = 0; ni < 4; ++ni) {
      int gcol = bn0 + wn + ni * 16 + row16;
      float bias = bih[gcol];
#pragma unroll
      for (int q = 0; q < 4; ++q) {
        float v = acc[mi][ni][q] + bias;
        size_t off = (size_t)(grow0 + q) * G3 + gcol;
        if (gi_is_f32) gi32[off] = v;
        else gi16[off] = f2bf(v);
      }
    }
  }
}

// ---------------- persistent GRU scan: batch-partitioned groups -------------
// 4 independent groups x 32 WGs. Group g owns batches [16g,16g+16); WG w owns
// 32 hidden units (96 gh cols = 6 MFMA col-tiles). Waves K-split 8x128.
// W fragments hoisted global->VGPR once (96 regs/lane); h_prev in a register.
// Per-WG h read = 32KB (was 128: the dominant per-step L3 stream).
// Barrier group-local: 2 sub-counters of 16 (relaxed monotonic RMW) -> 2-dword
// gen pair; tid0 polls pair with one dwordx2 sc0sc1 load. Groups drift freely.
// LDS: ghp[8][16][100] fp32 K-partials (pad 100 kills write bank conflicts).

#define LDH(dst, OFFS) asm volatile("global_load_dwordx4 %0, %1, off offset:" OFFS " sc0 sc1" : "=v"(dst) : "v"(hadr))
#define WAITV(N) do { asm volatile("s_waitcnt vmcnt(" #N ")" ::: "memory"); __builtin_amdgcn_sched_barrier(0); } while (0)

__global__ __launch_bounds__(512, 2) void gru_persist(
    const unsigned short* __restrict__ Whh_hi,
    const float* __restrict__ gi32, const unsigned short* __restrict__ gi16, int gi_is_f32,
    const float* __restrict__ bhh,
    unsigned short* __restrict__ h0, unsigned short* __restrict__ h1,
    unsigned* __restrict__ bar,
    float* __restrict__ out, float* __restrict__ hidden)
{
  __shared__ float ghp[8][16][100];   // 50KB K-split partials
  __shared__ char pin_[56 * 1024];    // occupancy pin -> 1 WG/CU
  const int tid = threadIdx.x;
  const int wg = blockIdx.x;
  const int g = wg >> 5, w = wg & 31;
  const int j0 = w * UPW;
  const int b0 = g * GB;

  if (gi_is_f32 == 2) pin_[tid] = 0;  // never true at runtime; keeps pin_ alive

  const int wave = tid >> 6, lane = tid & 63;
  const int kw = wave;                 // K-slice [kw*128, +128)
  const int row16 = lane & 15, koc = lane >> 4;

  // hoist this lane's W fragments: 6 col-tiles x 4 k-chunks, global -> VGPR
  s16x8 wr[24];
#pragma unroll
  for (int t = 0; t < 6; ++t) {
#pragma unroll
    for (int ck = 0; ck < 4; ++ck) {
      int wrow = (t >> 1) * HID + j0 + (t & 1) * 16 + row16;
      size_t byte = (size_t)wrow * 2048 + (size_t)(kw * 256 + ck * 64 + koc * 16);
      wr[t * 4 + ck] = *(const s16x8*)((const char*)Whh_hi + byte);
    }
  }

  const unsigned hvoff = (unsigned)((b0 + row16) * 2048 + kw * 256 + koc * 16);

  const int bb_l = tid >> 5, uu_l = tid & 31;  // thread -> (batch, unit)
  const int bb = b0 + bb_l, j = j0 + uu_l;
  const float bh_r = bhh[j], bh_z = bhh[HID + j], bh_n = bhh[2 * HID + j];
  float hprev = 0.f;

  unsigned* cA = bar;                  // 8 sub-counters (g*2+sub)*32, 128B apart
  unsigned* genv = bar + 512;          // group g pair at genv[g*32 + {0,1}]
  const int sub = w >> 4;

  for (int s = 0; s < SEQ; ++s) {
    const unsigned short* hin = (s & 1) ? h1 : h0;
    unsigned short* hout = (s & 1) ? h0 : h1;
    unsigned long long hadr = (unsigned long long)hin + hvoff;

    // gi prefetch (independent of h -> issue before barrier spin)
    float gir = 0.f, giz = 0.f, gin_ = 0.f;
    unsigned short g16r = 0, g16z = 0, g16n = 0;
    if (gi_is_f32) {
      unsigned long long ga = (unsigned long long)(gi32 + (size_t)(s * BATCH + bb) * G3 + j);
      asm volatile("global_load_dword %0, %1, off" : "=v"(gir) : "v"(ga));
      asm volatile("global_load_dword %0, %1, off" : "=v"(giz) : "v"(ga + 4096ull));
      asm volatile("global_load_dword %0, %1, off" : "=v"(gin_) : "v"(ga + 8192ull));
    } else {
      unsigned long long ga = (unsigned long long)(gi16 + (size_t)(s * BATCH + bb) * G3 + j);
      asm volatile("global_load_ushort %0, %1, off" : "=v"(g16r) : "v"(ga));
      asm volatile("global_load_ushort %0, %1, off" : "=v"(g16z) : "v"(ga + 2048ull));
      asm volatile("global_load_ushort %0, %1, off" : "=v"(g16n) : "v"(ga + 4096ull));
    }

    // group barrier wait: both sub-gens >= s (one dwordx2 sc0sc1 poll)
    if (tid == 0) {
      unsigned long long gva = (unsigned long long)(genv + g * 32);
      for (;;) {
        uint2 gg;
        asm volatile("global_load_dwordx2 %0, %1, off sc0 sc1\n\t"
                     "s_waitcnt vmcnt(0)"
                     : "=v"(gg) : "v"(gva) : "memory");
        if (umin2(gg.x, gg.y) >= (unsigned)s) break;
      }
    }
    __syncthreads();

    // h loads (4 x dwordx4 = this wave's 16 batches x 128 K) + MFMA from regs
    f32x4 acc[6] = {};
    s16x8 a0, a1, a2, a3;
    LDH(a0, "0"); LDH(a1, "64"); LDH(a2, "128"); LDH(a3, "192");
    WAITV(3);
#pragma unroll
    for (int t = 0; t < 6; ++t) acc[t] = __builtin_amdgcn_mfma_f32_16x16x32_bf16(a0, wr[t * 4 + 0], acc[t], 0, 0, 0);
    WAITV(2);
#pragma unroll
    for (int t = 0; t < 6; ++t) acc[t] = __builtin_amdgcn_mfma_f32_16x16x32_bf16(a1, wr[t * 4 + 1], acc[t], 0, 0, 0);
    WAITV(1);
#pragma unroll
    for (int t = 0; t < 6; ++t) acc[t] = __builtin_amdgcn_mfma_f32_16x16x32_bf16(a2, wr[t * 4 + 2], acc[t], 0, 0, 0);
    WAITV(0);
#pragma unroll
    for (int t = 0; t < 6; ++t) acc[t] = __builtin_amdgcn_mfma_f32_16x16x32_bf16(a3, wr[t * 4 + 3], acc[t], 0, 0, 0);

    // write K-partials: C row=(lane>>4)*4+q (batch), col=lane&15 (gh col)
#pragma unroll
    for (int t = 0; t < 6; ++t)
#pragma unroll
      for (int q = 0; q < 4; ++q)
        ghp[kw][koc * 4 + q][t * 16 + row16] = acc[t][q];
    __syncthreads();

    // reduce 8 K-partials + gating (thread owns one (batch, unit))
    float ghr = 0.f, ghz = 0.f, ghn = 0.f;
#pragma unroll
    for (int k2 = 0; k2 < 8; ++k2) {
      ghr += ghp[k2][bb_l][uu_l];
      ghz += ghp[k2][bb_l][32 + uu_l];
      ghn += ghp[k2][bb_l][64 + uu_l];
    }
    float ir, iz, inn;
    if (gi_is_f32) { ir = gir; iz = giz; inn = gin_; }
    else { ir = bf2f(g16r); iz = bf2f(g16z); inn = bf2f(g16n); }
    float r = 1.f / (1.f + __expf(-(ir + ghr + bh_r)));
    float z = 1.f / (1.f + __expf(-(iz + ghz + bh_z)));
    float n = tanhf(inn + r * (ghn + bh_n));
    float h = (1.f - z) * n + z * hprev;
    hprev = h;
    // h store FIRST (gates the barrier), then out/hidden (drain later)
    unsigned short hb = f2bf(h);
    unsigned long long sha = (unsigned long long)hout + (unsigned)(bb * 1024 + j) * 2u;
    asm volatile("global_store_short %0, %1, off sc0 sc1" :: "v"(sha), "v"(hb) : "memory");
    out[((size_t)bb * SEQ + s) * HID + j] = h;
    if (s == SEQ - 1) hidden[(size_t)bb * HID + j] = h;
    // wait for the h store (oldest); the out store may keep draining
    asm volatile("s_waitcnt vmcnt(1)" ::: "memory");
    __syncthreads();   // also guards ghp reuse

    // arrive: relaxed monotonic sub-counter; 16th writes its gen dword
    if (tid == 0) {
      unsigned a = __hip_atomic_fetch_add(&cA[(g * 2 + sub) * 32], 1u, __ATOMIC_RELAXED, __HIP_MEMORY_SCOPE_AGENT);
      if (a + 1u == 16u * (unsigned)(s + 1)) {
        __hip_atomic_store(&genv[g * 32 + sub], (unsigned)(s + 1), __ATOMIC_RELAXED, __HIP_MEMORY_SCOPE_AGENT);
      }
    }
  }
}

extern "C" void kernel_launch(void* const* d_in, const int* in_sizes, int n_in,
                              void* d_out, int out_size, void* d_ws, size_t ws_size,
                              hipStream_t stream) {
  const float* emb = (const float*)d_in[0];
  const float* wih = (const float*)d_in[1];
  const float* whh = (const float*)d_in[2];
  const float* bih = (const float*)d_in[3];
  const float* bhh = (const float*)d_in[4];
  float* out = (float*)d_out;                          // [64][512][1024]
  float* hidden = out + (size_t)BATCH * SEQ * HID;     // [64][1024]

  char* ws = (char*)d_ws;
  size_t off = 0;
  auto alloc = [&](size_t bytes) {
    char* p = ws + off;
    off += (bytes + 255) & ~(size_t)255;
    return p;
  };

  unsigned short* emb_hi = (unsigned short*)alloc((size_t)MTOT * IN_DIM * 2);
  unsigned short* emb_lo = (unsigned short*)alloc((size_t)MTOT * IN_DIM * 2);
  unsigned short* wih_hi = (unsigned short*)alloc((size_t)G3 * IN_DIM * 2);
  unsigned short* wih_lo = (unsigned short*)alloc((size_t)G3 * IN_DIM * 2);
  unsigned short* whh_hi = (unsigned short*)alloc((size_t)G3 * HID * 2);
  unsigned short* whh_lo = (unsigned short*)alloc((size_t)G3 * HID * 2);
  unsigned short* hbuf   = (unsigned short*)alloc((size_t)2 * BATCH * HID * 2);
  unsigned* bar = (unsigned*)alloc(4096);

  size_t gi32_bytes = (size_t)MTOT * G3 * 4;
  int gi_is_f32 = (off + gi32_bytes <= ws_size) ? 1 : 0;
  float* gi32 = nullptr;
  unsigned short* gi16 = nullptr;
  if (gi_is_f32) gi32 = (float*)alloc(gi32_bytes);
  else           gi16 = (unsigned short*)alloc((size_t)MTOT * G3 * 2);

  // converts
  split_kernel<<<4096, 256, 0, stream>>>(emb, emb_hi, emb_lo, MTOT * IN_DIM / 4);
  split_kernel<<<1536, 256, 0, stream>>>(wih, wih_hi, wih_lo, G3 * IN_DIM / 4);
  split_kernel<<<3072, 256, 0, stream>>>(whh, whh_hi, whh_lo, G3 * HID / 4);

  // zero h state (h0 = 0) + barrier state (counters must restart at 0 every call)
  (void)hipMemsetAsync(hbuf, 0, (size_t)2 * BATCH * HID * 2, stream);
  (void)hipMemsetAsync(bar, 0, 4096, stream);

  // phase 1 GEMM (stage-once hi/lo)
  dim3 g1(MTOT / 128, G3 / 128);
  gemm_gi<<<g1, 256, 0, stream>>>(emb_hi, emb_lo, wih_hi, wih_lo, bih, gi32, gi16, gi_is_f32);

  // persistent scan (cooperative: guarantees all 128 WGs co-resident)
  size_t BH = (size_t)BATCH * HID;
  unsigned short* h0 = hbuf;
  unsigned short* h1 = hbuf + BH;
  void* args[] = { &whh_hi, &gi32, &gi16, &gi_is_f32, &bhh,
                   &h0, &h1, &bar, &out, &hidden };
  (void)hipLaunchCooperativeKernel((void*)gru_persist, dim3(NWG), dim3(512), args, 0, stream);
}

// Round 14
// 2081.549 us; speedup vs baseline: 2.7511x; 1.3342x over previous
//
#include <hip/hip_runtime.h>
#include <hip/hip_bf16.h>

#define SEQ 512
#define BATCH 64
#define IN_DIM 512
#define HID 1024
#define G3 3072          // 3*HID
#define MTOT 32768       // SEQ*BATCH
#define GB 16            // batches per group (4 groups)
#define UPW 32           // hidden units per WG

typedef float f32x4 __attribute__((ext_vector_type(4)));
typedef short s16x8 __attribute__((ext_vector_type(8)));

static __device__ __forceinline__ unsigned short f2bf(float f) {
  union { float f; unsigned u; } v; v.f = f;
  unsigned r = v.u + 0x7fffu + ((v.u >> 16) & 1u);
  return (unsigned short)(r >> 16);
}
static __device__ __forceinline__ float bf2f(unsigned short b) {
  union { unsigned u; float f; } v; v.u = ((unsigned)b) << 16;
  return v.f;
}
static __device__ __forceinline__ unsigned umin2(unsigned a, unsigned b) { return a < b ? a : b; }

// ---------------- fp32 -> bf16 hi/lo split ----------------
__global__ __launch_bounds__(256) void split_kernel(const float* __restrict__ src,
    unsigned short* __restrict__ hi, unsigned short* __restrict__ lo, int n4) {
  int stride = gridDim.x * blockDim.x;
  for (int i = blockIdx.x * blockDim.x + threadIdx.x; i < n4; i += stride) {
    float4 v = ((const float4*)src)[i];
    ushort4 h, l;
    h.x = f2bf(v.x); l.x = f2bf(v.x - bf2f(h.x));
    h.y = f2bf(v.y); l.y = f2bf(v.y - bf2f(h.y));
    h.z = f2bf(v.z); l.z = f2bf(v.z - bf2f(h.z));
    h.w = f2bf(v.w); l.w = f2bf(v.w - bf2f(h.w));
    ((ushort4*)hi)[i] = h;
    ((ushort4*)lo)[i] = l;
  }
}

// ---------------- fused cooperative kernel ----------------
// 256 WGs x 512 thr, 114KB LDS -> exactly 1 WG/CU (co-residency guaranteed).
// WGs 0-127: batch-partitioned GRU scan (round-13 structure).
// WGs 128-255: gi GEMM workers, s-major job order; slab bm (=steps 2bm,2bm+1)
//   ready when cnt[bm]==24. Stores sc0sc1 -> vmcnt(0) -> barrier -> relaxed
//   atomic inc (same proven causality chain as the h barrier).
// Scan gates step s on {h gen pair >= s} AND {cnt[s>>1] >= 24} in ONE poll.

#define LDH(dst, OFFS) asm volatile("global_load_dwordx4 %0, %1, off offset:" OFFS " sc0 sc1" : "=v"(dst) : "v"(hadr))
#define WAITV(N) do { asm volatile("s_waitcnt vmcnt(" #N ")" ::: "memory"); __builtin_amdgcn_sched_barrier(0); } while (0)

__global__ __launch_bounds__(512, 2) void gru_fused(
    const unsigned short* __restrict__ Whh_hi,
    const unsigned short* __restrict__ emb_hi, const unsigned short* __restrict__ emb_lo,
    const unsigned short* __restrict__ wih_hi, const unsigned short* __restrict__ wih_lo,
    const float* __restrict__ bih,
    float* __restrict__ gi32, unsigned short* __restrict__ gi16, int gi_is_f32,
    const float* __restrict__ bhh,
    unsigned short* __restrict__ h0, unsigned short* __restrict__ h1,
    unsigned* __restrict__ bar,
    float* __restrict__ out, float* __restrict__ hidden)
{
  __shared__ float ghp[8][16][100];        // 50KB (scan role)
  __shared__ unsigned short Ah[128 * 64];  // 16KB (gemm role)
  __shared__ unsigned short Alo_[128 * 64];
  __shared__ unsigned short Bh[128 * 64];
  __shared__ unsigned short Blo_[128 * 64];   // 114KB total -> 1 WG/CU
  const int tid = threadIdx.x;
  const int wg = blockIdx.x;
  const int wave = tid >> 6, lane = tid & 63;
  const int row16 = lane & 15;

  unsigned* cnt = bar;                 // cnt[0..255] slab counters
  unsigned* cA = bar + 256;            // scan arrive counters, 128B apart
  unsigned* genv = bar + 768;          // scan gen dwords, genv[g*32+sub]

  if (wg >= 128) {
    // ================= GEMM worker role =================
    const int widx = wg - 128;
    const int wm = (wave >> 2) * 64, wn = (wave & 3) * 32;
    const int kq = lane >> 4;
    const int srow = tid >> 3;     // 0..63
    const int skc = tid & 7;       // 16B chunk in 128B row

    for (int it = 0; it < 48; ++it) {
      int q = widx + it * 128;
      int bm = q / 24, bn = q - bm * 24;
      int bm0 = bm * 128, bn0 = bn * 128;

      f32x4 acc[4][2] = {};
      for (int kt = 0; kt < IN_DIM / 64; ++kt) {
        uint4 rah[2], ral[2], rbh[2], rbl[2];
        for (int i = 0; i < 2; ++i) {
          int r = i * 64 + srow;
          size_t ao = (size_t)(bm0 + r) * IN_DIM + kt * 64 + skc * 8;
          size_t bo = (size_t)(bn0 + r) * IN_DIM + kt * 64 + skc * 8;
          rah[i] = *(const uint4*)&emb_hi[ao];
          ral[i] = *(const uint4*)&emb_lo[ao];
          rbh[i] = *(const uint4*)&wih_hi[bo];
          rbl[i] = *(const uint4*)&wih_lo[bo];
        }
        __syncthreads();
        for (int i = 0; i < 2; ++i) {
          int r = i * 64 + srow;
          *(uint4*)&Ah[r * 64 + skc * 8]   = rah[i];
          *(uint4*)&Alo_[r * 64 + skc * 8] = ral[i];
          *(uint4*)&Bh[r * 64 + skc * 8]   = rbh[i];
          *(uint4*)&Blo_[r * 64 + skc * 8] = rbl[i];
        }
        __syncthreads();
        for (int kk = 0; kk < 2; ++kk) {
          s16x8 ah[4], al[4], bh[2], bl[2];
          for (int mi = 0; mi < 4; ++mi) {
            int off = (wm + mi * 16 + row16) * 64 + kk * 32 + kq * 8;
            ah[mi] = *(const s16x8*)&Ah[off];
            al[mi] = *(const s16x8*)&Alo_[off];
          }
          for (int ni = 0; ni < 2; ++ni) {
            int off = (wn + ni * 16 + row16) * 64 + kk * 32 + kq * 8;
            bh[ni] = *(const s16x8*)&Bh[off];
            bl[ni] = *(const s16x8*)&Blo_[off];
          }
          for (int mi = 0; mi < 4; ++mi)
            for (int ni = 0; ni < 2; ++ni) {
              acc[mi][ni] = __builtin_amdgcn_mfma_f32_16x16x32_bf16(ah[mi], bh[ni], acc[mi][ni], 0, 0, 0);
              acc[mi][ni] = __builtin_amdgcn_mfma_f32_16x16x32_bf16(al[mi], bh[ni], acc[mi][ni], 0, 0, 0);
              acc[mi][ni] = __builtin_amdgcn_mfma_f32_16x16x32_bf16(ah[mi], bl[ni], acc[mi][ni], 0, 0, 0);
            }
        }
      }
      // epilogue: sc0sc1 write-through stores (visible at coherent point)
      for (int mi = 0; mi < 4; ++mi) {
        int grow0 = bm0 + wm + mi * 16 + kq * 4;
        for (int ni = 0; ni < 2; ++ni) {
          int gcol = bn0 + wn + ni * 16 + row16;
          float bias = bih[gcol];
#pragma unroll
          for (int qq = 0; qq < 4; ++qq) {
            float v = acc[mi][ni][qq] + bias;
            size_t off = (size_t)(grow0 + qq) * G3 + gcol;
            if (gi_is_f32) {
              unsigned long long ad = (unsigned long long)(gi32 + off);
              asm volatile("global_store_dword %0, %1, off sc0 sc1" :: "v"(ad), "v"(v) : "memory");
            } else {
              unsigned short bv = f2bf(v);
              unsigned long long ad = (unsigned long long)(gi16 + off);
              asm volatile("global_store_short %0, %1, off sc0 sc1" :: "v"(ad), "v"(bv) : "memory");
            }
          }
        }
      }
      asm volatile("s_waitcnt vmcnt(0)" ::: "memory");
      __syncthreads();   // whole WG's stores acked
      if (tid == 0)
        __hip_atomic_fetch_add(&cnt[bm], 1u, __ATOMIC_RELAXED, __HIP_MEMORY_SCOPE_AGENT);
    }
    return;
  }

  // ================= scan role (round-13 structure) =================
  const int g = wg >> 5, w = wg & 31;
  const int j0 = w * UPW;
  const int b0 = g * GB;
  const int kw = wave;
  const int koc = lane >> 4;

  // hoist this lane's W fragments: 6 col-tiles x 4 k-chunks, global -> VGPR
  s16x8 wr[24];
#pragma unroll
  for (int t = 0; t < 6; ++t) {
#pragma unroll
    for (int ck = 0; ck < 4; ++ck) {
      int wrow = (t >> 1) * HID + j0 + (t & 1) * 16 + row16;
      size_t byte = (size_t)wrow * 2048 + (size_t)(kw * 256 + ck * 64 + koc * 16);
      wr[t * 4 + ck] = *(const s16x8*)((const char*)Whh_hi + byte);
    }
  }

  const unsigned hvoff = (unsigned)((b0 + row16) * 2048 + kw * 256 + koc * 16);
  const int bb_l = tid >> 5, uu_l = tid & 31;
  const int bb = b0 + bb_l, j = j0 + uu_l;
  const float bh_r = bhh[j], bh_z = bhh[HID + j], bh_n = bhh[2 * HID + j];
  float hprev = 0.f;
  const int sub = w >> 4;

  for (int s = 0; s < SEQ; ++s) {
    const unsigned short* hin = (s & 1) ? h1 : h0;
    unsigned short* hout = (s & 1) ? h0 : h1;
    unsigned long long hadr = (unsigned long long)hin + hvoff;

    // combined wait: h gen pair >= s AND gi slab (s>>1) complete
    if (tid == 0) {
      unsigned long long gva = (unsigned long long)(genv + g * 32);
      unsigned long long cva = (unsigned long long)(cnt + (s >> 1));
      for (;;) {
        uint2 gg; unsigned cc;
        asm volatile("global_load_dwordx2 %0, %2, off sc0 sc1\n\t"
                     "global_load_dword %1, %3, off sc0 sc1\n\t"
                     "s_waitcnt vmcnt(0)"
                     : "=v"(gg), "=v"(cc) : "v"(gva), "v"(cva) : "memory");
        if (umin2(gg.x, gg.y) >= (unsigned)s && cc >= 24u) break;
      }
    }
    __syncthreads();

    // gi loads (now gated by slab counter) -- issued first, retire in WAITV(3)
    float gir = 0.f, giz = 0.f, gin_ = 0.f;
    unsigned short g16r = 0, g16z = 0, g16n = 0;
    if (gi_is_f32) {
      unsigned long long ga = (unsigned long long)(gi32 + (size_t)(s * BATCH + bb) * G3 + j);
      asm volatile("global_load_dword %0, %1, off sc0 sc1" : "=v"(gir) : "v"(ga));
      asm volatile("global_load_dword %0, %1, off sc0 sc1" : "=v"(giz) : "v"(ga + 4096ull));
      asm volatile("global_load_dword %0, %1, off sc0 sc1" : "=v"(gin_) : "v"(ga + 8192ull));
    } else {
      unsigned long long ga = (unsigned long long)(gi16 + (size_t)(s * BATCH + bb) * G3 + j);
      asm volatile("global_load_ushort %0, %1, off sc0 sc1" : "=v"(g16r) : "v"(ga));
      asm volatile("global_load_ushort %0, %1, off sc0 sc1" : "=v"(g16z) : "v"(ga + 2048ull));
      asm volatile("global_load_ushort %0, %1, off sc0 sc1" : "=v"(g16n) : "v"(ga + 4096ull));
    }

    // h loads (4 x dwordx4) + MFMA from registers
    f32x4 acc[6] = {};
    s16x8 a0, a1, a2, a3;
    LDH(a0, "0"); LDH(a1, "64"); LDH(a2, "128"); LDH(a3, "192");
    WAITV(3);
#pragma unroll
    for (int t = 0; t < 6; ++t) acc[t] = __builtin_amdgcn_mfma_f32_16x16x32_bf16(a0, wr[t * 4 + 0], acc[t], 0, 0, 0);
    WAITV(2);
#pragma unroll
    for (int t = 0; t < 6; ++t) acc[t] = __builtin_amdgcn_mfma_f32_16x16x32_bf16(a1, wr[t * 4 + 1], acc[t], 0, 0, 0);
    WAITV(1);
#pragma unroll
    for (int t = 0; t < 6; ++t) acc[t] = __builtin_amdgcn_mfma_f32_16x16x32_bf16(a2, wr[t * 4 + 2], acc[t], 0, 0, 0);
    WAITV(0);
#pragma unroll
    for (int t = 0; t < 6; ++t) acc[t] = __builtin_amdgcn_mfma_f32_16x16x32_bf16(a3, wr[t * 4 + 3], acc[t], 0, 0, 0);

#pragma unroll
    for (int t = 0; t < 6; ++t)
#pragma unroll
      for (int qq = 0; qq < 4; ++qq)
        ghp[kw][koc * 4 + qq][t * 16 + row16] = acc[t][qq];
    __syncthreads();

    // reduce 8 K-partials + gating
    float ghr = 0.f, ghz = 0.f, ghn = 0.f;
#pragma unroll
    for (int k2 = 0; k2 < 8; ++k2) {
      ghr += ghp[k2][bb_l][uu_l];
      ghz += ghp[k2][bb_l][32 + uu_l];
      ghn += ghp[k2][bb_l][64 + uu_l];
    }
    float ir, iz, inn;
    if (gi_is_f32) { ir = gir; iz = giz; inn = gin_; }
    else { ir = bf2f(g16r); iz = bf2f(g16z); inn = bf2f(g16n); }
    float r = 1.f / (1.f + __expf(-(ir + ghr + bh_r)));
    float z = 1.f / (1.f + __expf(-(iz + ghz + bh_z)));
    float n = tanhf(inn + r * (ghn + bh_n));
    float h = (1.f - z) * n + z * hprev;
    hprev = h;
    unsigned short hb = f2bf(h);
    unsigned long long sha = (unsigned long long)hout + (unsigned)(bb * 1024 + j) * 2u;
    asm volatile("global_store_short %0, %1, off sc0 sc1" :: "v"(sha), "v"(hb) : "memory");
    out[((size_t)bb * SEQ + s) * HID + j] = h;
    if (s == SEQ - 1) hidden[(size_t)bb * HID + j] = h;
    asm volatile("s_waitcnt vmcnt(1)" ::: "memory");
    __syncthreads();   // h acked + ghp reuse guard

    if (tid == 0) {
      unsigned a = __hip_atomic_fetch_add(&cA[(g * 2 + sub) * 32], 1u, __ATOMIC_RELAXED, __HIP_MEMORY_SCOPE_AGENT);
      if (a + 1u == 16u * (unsigned)(s + 1)) {
        __hip_atomic_store(&genv[g * 32 + sub], (unsigned)(s + 1), __ATOMIC_RELAXED, __HIP_MEMORY_SCOPE_AGENT);
      }
    }
  }
}

extern "C" void kernel_launch(void* const* d_in, const int* in_sizes, int n_in,
                              void* d_out, int out_size, void* d_ws, size_t ws_size,
                              hipStream_t stream) {
  const float* emb = (const float*)d_in[0];
  const float* wih = (const float*)d_in[1];
  const float* whh = (const float*)d_in[2];
  const float* bih = (const float*)d_in[3];
  const float* bhh = (const float*)d_in[4];
  float* out = (float*)d_out;                          // [64][512][1024]
  float* hidden = out + (size_t)BATCH * SEQ * HID;     // [64][1024]

  char* ws = (char*)d_ws;
  size_t off = 0;
  auto alloc = [&](size_t bytes) {
    char* p = ws + off;
    off += (bytes + 255) & ~(size_t)255;
    return p;
  };

  unsigned short* emb_hi = (unsigned short*)alloc((size_t)MTOT * IN_DIM * 2);
  unsigned short* emb_lo = (unsigned short*)alloc((size_t)MTOT * IN_DIM * 2);
  unsigned short* wih_hi = (unsigned short*)alloc((size_t)G3 * IN_DIM * 2);
  unsigned short* wih_lo = (unsigned short*)alloc((size_t)G3 * IN_DIM * 2);
  unsigned short* whh_hi = (unsigned short*)alloc((size_t)G3 * HID * 2);
  unsigned short* whh_lo = (unsigned short*)alloc((size_t)G3 * HID * 2);
  unsigned short* hbuf   = (unsigned short*)alloc((size_t)2 * BATCH * HID * 2);
  unsigned* bar = (unsigned*)alloc(8192);

  size_t gi32_bytes = (size_t)MTOT * G3 * 4;
  int gi_is_f32 = (off + gi32_bytes <= ws_size) ? 1 : 0;
  float* gi32 = nullptr;
  unsigned short* gi16 = nullptr;
  if (gi_is_f32) gi32 = (float*)alloc(gi32_bytes);
  else           gi16 = (unsigned short*)alloc((size_t)MTOT * G3 * 2);

  // converts (whh split kept only for hi half used by the scan)
  split_kernel<<<4096, 256, 0, stream>>>(emb, emb_hi, emb_lo, MTOT * IN_DIM / 4);
  split_kernel<<<1536, 256, 0, stream>>>(wih, wih_hi, wih_lo, G3 * IN_DIM / 4);
  split_kernel<<<3072, 256, 0, stream>>>(whh, whh_hi, whh_lo, G3 * HID / 4);

  // zero h state + all barrier/slab counters (must reset every call/replay)
  (void)hipMemsetAsync(hbuf, 0, (size_t)2 * BATCH * HID * 2, stream);
  (void)hipMemsetAsync(bar, 0, 8192, stream);

  // fused cooperative launch: 128 scan WGs + 128 gemm workers, 1 WG/CU
  size_t BH = (size_t)BATCH * HID;
  unsigned short* h0 = hbuf;
  unsigned short* h1 = hbuf + BH;
  void* args[] = { &whh_hi, &emb_hi, &emb_lo, &wih_hi, &wih_lo, &bih,
                   &gi32, &gi16, &gi_is_f32, &bhh,
                   &h0, &h1, &bar, &out, &hidden };
  (void)hipLaunchCooperativeKernel((void*)gru_fused, dim3(256), dim3(512), args, 0, stream);
}